// Round 17
// baseline (393.928 us; speedup 1.0000x reference)
//
#include <hip/hip_runtime.h>
#include <hip/hip_bf16.h>

#define NN 100000
#define EPR 1600000
#define FIN 256
#define FOUT 64
#define BSZ 64            // S-side nodes per bucket
#define NB 1563           // ceil(100000/64)  (S side)
#define NBP 1568
#define BSZD 32           // D-side nodes per bucket
#define NBD 3125          // 100000/32 exactly
#define NBPD 3136
#define CHUNK 4096
#define NBLK 391          // ceil(EPR/CHUNK)
#define EPT 16            // edges per thread in hist/place
#define CAP2 2048         // aggsort LDS capacity (mean 512, sd ~22)
#define HSTRIDE ((size_t)(NN + 1) * FOUT)   // hsb rows per relation incl. zero row

typedef __attribute__((ext_vector_type(8))) short short8;
typedef __attribute__((ext_vector_type(4))) float f32x4;

__device__ __forceinline__ unsigned short f2bf(float f) {
    unsigned u = __float_as_uint(f);
    u = (u + 0x7FFFu + ((u >> 16) & 1u)) >> 16;   // RTN-even
    return (unsigned short)u;
}
__device__ __forceinline__ float uaf(unsigned u) { return __uint_as_float(u); }
__device__ __forceinline__ void unpk(f32x4& seg, uint2 u) {
    seg.x += uaf(u.x << 16); seg.y += uaf(u.x & 0xFFFF0000u);
    seg.z += uaf(u.y << 16); seg.w += uaf(u.y & 0xFFFF0000u);
}

// ---------------- per-(block,relation) bucket histograms ----------------
__global__ __launch_bounds__(256) void hist_all_kernel(const int* __restrict__ ei,
                                                       unsigned* __restrict__ btabD4,
                                                       unsigned* __restrict__ btabS4) {
    __shared__ unsigned hD[NBD], hS[NB];
    int tid = threadIdx.x, r = blockIdx.y, blk = blockIdx.x;
    const int* src = ei + (size_t)r * 2 * EPR;
    const int* dst = src + EPR;
    for (int i = tid; i < NBD; i += 256) hD[i] = 0;
    for (int i = tid; i < NB; i += 256) hS[i] = 0;
    __syncthreads();
    int e0 = blk * CHUNK;
    #pragma unroll
    for (int t = 0; t < EPT; ++t) {
        int e = e0 + t * 256 + tid;
        if (e < EPR) {
            atomicAdd(&hS[src[e] >> 6], 1u);
            atomicAdd(&hD[dst[e] >> 5], 1u);
        }
    }
    __syncthreads();
    size_t rowD = ((size_t)r * NBLK + blk) * NBPD;
    for (int i = tid; i < NBD; i += 256) btabD4[rowD + i] = hD[i];
    size_t rowS = ((size_t)r * NBLK + blk) * NBP;
    for (int i = tid; i < NB; i += 256) btabS4[rowS + i] = hS[i];
}

// ---------------- per-bucket exclusive scan over blocks + totals ----------------
__global__ __launch_bounds__(256) void btot_all_kernel(unsigned* __restrict__ btabD4,
                                                       unsigned* __restrict__ btabS4,
                                                       unsigned* __restrict__ totD4,
                                                       unsigned* __restrict__ totS4) {
    int r = blockIdx.z;
    int isS = blockIdx.y;
    int NBcur = isS ? NB : NBD;
    size_t NBPcur = isS ? NBP : NBPD;
    unsigned* tab = (isS ? btabS4 : btabD4) + (size_t)r * NBLK * NBPcur;
    unsigned* tot = (isS ? totS4 : totD4) + (size_t)r * NBPcur;
    __shared__ unsigned tile[NBLK][8];
    int b0 = blockIdx.x * 8;
    for (int idx = threadIdx.x; idx < NBLK * 8; idx += 256) {
        int blk = idx >> 3, bb = idx & 7;
        int b = b0 + bb;
        tile[blk][bb] = (b < NBcur) ? tab[(size_t)blk * NBPcur + b] : 0u;
    }
    __syncthreads();
    if (threadIdx.x < 8) {
        int bb = threadIdx.x;
        unsigned s = 0;
        for (int blk = 0; blk < NBLK; ++blk) {
            unsigned v = tile[blk][bb];
            tile[blk][bb] = s;
            s += v;
        }
        if (b0 + bb < NBcur) tot[b0 + bb] = s;
    }
    __syncthreads();
    for (int idx = threadIdx.x; idx < NBLK * 8; idx += 256) {
        int blk = idx >> 3, bb = idx & 7;
        int b = b0 + bb;
        if (b < NBcur) tab[(size_t)blk * NBPcur + b] = tile[blk][bb];
    }
}

// ---------------- exclusive scan of bucket totals -> global bases ----------------
__global__ void scan_all_kernel(const unsigned* __restrict__ totD4, const unsigned* __restrict__ totS4,
                                unsigned* __restrict__ gbaseD4, unsigned* __restrict__ gbaseS4) {
    int r = blockIdx.y;
    int isS = blockIdx.x;
    int NBcur = isS ? NB : NBD;
    size_t NBPcur = isS ? NBP : NBPD;
    const unsigned* tot = (isS ? totS4 : totD4) + (size_t)r * NBPcur;
    unsigned* gb = (isS ? gbaseS4 : gbaseD4) + (size_t)r * NBPcur;
    __shared__ unsigned sc[256];
    int tid = threadIdx.x;
    unsigned loc[16]; unsigned s = 0;
    #pragma unroll
    for (int k = 0; k < 16; ++k) {
        int idx = tid * 16 + k;
        unsigned v = (idx < NBcur) ? tot[idx] : 0u;
        loc[k] = s; s += v;
    }
    sc[tid] = s; __syncthreads();
    for (int off = 1; off < 256; off <<= 1) {
        unsigned a = (tid >= off) ? sc[tid - off] : 0u;
        __syncthreads(); sc[tid] += a; __syncthreads();
    }
    unsigned texcl = tid ? sc[tid - 1] : 0u;
    #pragma unroll
    for (int k = 0; k < 16; ++k) {
        int idx = tid * 16 + k;
        if (idx < NBcur) gb[idx] = texcl + loc[k];
    }
}

// ---------------- fused placement: D records then S bytes, edges read ONCE ----------------
// D record: bits[23:0] = src byte-offset (src*128), bits[28:24] = dst local id (5b)
// buf2 slot: (bucket << 13) | rank   (rank < 4096)
__global__ __launch_bounds__(256) void place_all_kernel(const int* __restrict__ ei,
                                                        const unsigned* __restrict__ gbaseD4,
                                                        const unsigned* __restrict__ btabD4,
                                                        unsigned* __restrict__ pairs4,
                                                        const unsigned* __restrict__ gbaseS4,
                                                        const unsigned* __restrict__ btabS4,
                                                        unsigned char* __restrict__ pairs2_4) {
    __shared__ unsigned h[NBD], hloc[NBD], sc[256];
    __shared__ unsigned buf[CHUNK], buf2[CHUNK];
    int tid = threadIdx.x, blk = blockIdx.x, r = blockIdx.y;
    const int* src = ei + (size_t)r * 2 * EPR;
    const int* dst = src + EPR;
    int e0 = blk * CHUNK;
    int csize = EPR - e0; if (csize > CHUNK) csize = CHUNK;

    int es[EPT], ed[EPT];
    #pragma unroll
    for (int t = 0; t < EPT; ++t) {
        int e = e0 + t * 256 + tid;
        if (e < EPR) { es[t] = src[e]; ed[t] = dst[e]; }
        else { es[t] = -1; ed[t] = 0; }
    }

    // ================= D phase (buckets of 32, NBD) =================
    for (int i = tid; i < NBD; i += 256) h[i] = 0;
    __syncthreads();
    #pragma unroll
    for (int t = 0; t < EPT; ++t)
        if (es[t] >= 0) atomicAdd(&h[ed[t] >> 5], 1u);
    __syncthreads();
    {
        unsigned loc[16]; unsigned s = 0;
        #pragma unroll
        for (int k = 0; k < 16; ++k) {
            int idx = tid * 16 + k;
            unsigned v = (idx < NBD) ? h[idx] : 0u;
            loc[k] = s; s += v;
        }
        sc[tid] = s; __syncthreads();
        for (int off = 1; off < 256; off <<= 1) {
            unsigned a = (tid >= off) ? sc[tid - off] : 0u;
            __syncthreads(); sc[tid] += a; __syncthreads();
        }
        unsigned texcl = tid ? sc[tid - 1] : 0u;
        #pragma unroll
        for (int k = 0; k < 16; ++k) {
            int idx = tid * 16 + k;
            if (idx < NBD) hloc[idx] = texcl + loc[k];
        }
    }
    __syncthreads();
    for (int i = tid; i < NBD; i += 256) h[i] = 0;
    __syncthreads();
    #pragma unroll
    for (int t = 0; t < EPT; ++t) {
        if (es[t] >= 0) {
            int b = ed[t] >> 5;
            unsigned rk = atomicAdd(&h[b], 1u);
            unsigned slot = hloc[b] + rk;
            buf[slot] = ((unsigned)es[t] << 7) | ((unsigned)(ed[t] & 31) << 24);
            buf2[slot] = ((unsigned)b << 13) | rk;
        }
    }
    __syncthreads();
    {
        unsigned* pairs = pairs4 + (size_t)r * EPR;
        const unsigned* gb = gbaseD4 + (size_t)r * NBPD;
        const unsigned* pb = btabD4 + ((size_t)r * NBLK + blk) * NBPD;
        for (int k = tid; k < csize; k += 256) {
            unsigned u = buf2[k];
            unsigned bb = u >> 13, rk = u & 8191u;
            pairs[gb[bb] + pb[bb] + rk] = buf[k];
        }
    }
    __syncthreads();

    // ================= S phase (buckets of 64, NB; reuses LDS) =================
    for (int i = tid; i < NB; i += 256) h[i] = 0;
    __syncthreads();
    #pragma unroll
    for (int t = 0; t < EPT; ++t)
        if (es[t] >= 0) atomicAdd(&h[es[t] >> 6], 1u);
    __syncthreads();
    {
        unsigned loc[16]; unsigned s = 0;
        #pragma unroll
        for (int k = 0; k < 16; ++k) {
            int idx = tid * 16 + k;
            unsigned v = (idx < NB) ? h[idx] : 0u;
            loc[k] = s; s += v;
        }
        sc[tid] = s; __syncthreads();
        for (int off = 1; off < 256; off <<= 1) {
            unsigned a = (tid >= off) ? sc[tid - off] : 0u;
            __syncthreads(); sc[tid] += a; __syncthreads();
        }
        unsigned texcl = tid ? sc[tid - 1] : 0u;
        #pragma unroll
        for (int k = 0; k < 16; ++k) {
            int idx = tid * 16 + k;
            if (idx < NB) hloc[idx] = texcl + loc[k];
        }
    }
    __syncthreads();
    for (int i = tid; i < NB; i += 256) h[i] = 0;
    __syncthreads();
    {
        unsigned char* bufB = (unsigned char*)buf;   // alias D buffer as bytes
        #pragma unroll
        for (int t = 0; t < EPT; ++t) {
            if (es[t] >= 0) {
                int b = es[t] >> 6;
                unsigned rk = atomicAdd(&h[b], 1u);
                unsigned slot = hloc[b] + rk;
                bufB[slot] = (unsigned char)(es[t] & 63);
                buf2[slot] = ((unsigned)b << 13) | rk;
            }
        }
        __syncthreads();
        unsigned char* pairs2 = pairs2_4 + (size_t)r * EPR;
        const unsigned* gb = gbaseS4 + (size_t)r * NBP;
        const unsigned* pb = btabS4 + ((size_t)r * NBLK + blk) * NBP;
        for (int k = tid; k < csize; k += 256) {
            unsigned u = buf2[k];
            unsigned bb = u >> 13, rk = u & 8191u;
            pairs2[gb[bb] + pb[bb] + rk] = bufB[k];
        }
    }
}

// ---------------- out-degree per node -> ns = rsqrt ----------------
__global__ void srcdeg_all_kernel(const unsigned char* __restrict__ pairs2_4,
                                  const unsigned* __restrict__ gbaseS4,
                                  const unsigned* __restrict__ totS4,
                                  float* __restrict__ nsb4) {
    __shared__ unsigned cnt[BSZ];
    int tid = threadIdx.x, b = blockIdx.x, r = blockIdx.y;
    const unsigned char* pairs2 = pairs2_4 + (size_t)r * EPR;
    if (tid < BSZ) cnt[tid] = 0;
    __syncthreads();
    unsigned st = gbaseS4[(size_t)r * NBP + b];
    int n = (int)totS4[(size_t)r * NBP + b];
    for (int i = tid; i < n; i += 256)
        atomicAdd(&cnt[pairs2[st + i]], 1u);
    __syncthreads();
    if (tid < BSZ) {
        int node = b * BSZ + tid;
        if (node < NN) {
            unsigned c = cnt[tid]; if (c < 1u) c = 1u;
            nsb4[(size_t)r * NN + node] = rsqrtf((float)c);
        }
    }
}

// ---------------- fused 4-relation bf16 MFMA GEMM: x tile loaded ONCE ----------------
__global__ __launch_bounds__(256, 2) void gemm4_kernel(const float* __restrict__ x,
                                                       const float* __restrict__ W,
                                                       unsigned short* __restrict__ hsb4,
                                                       const float* __restrict__ nsb4) {
    __shared__ unsigned short xs[128][40];      // [m][k] bf16
    __shared__ unsigned short wt[4][64][40];    // [r][n][k] bf16
    int tid = threadIdx.x;
    int wave = tid >> 6, lane = tid & 63;
    int wm = (wave >> 1) * 64;
    int wn = (wave & 1) * 32;
    int m0 = blockIdx.x * 128;

    f32x4 acc[4][4][2];
    #pragma unroll
    for (int r = 0; r < 4; ++r)
        #pragma unroll
        for (int mi = 0; mi < 4; ++mi)
            #pragma unroll
            for (int ni = 0; ni < 2; ++ni)
                acc[r][mi][ni] = (f32x4){0.f, 0.f, 0.f, 0.f};

    int srow = tid >> 1, skp = (tid & 1) * 16;
    int swn = tid >> 2, skq = (tid & 3) * 8;
    int gr = m0 + srow; if (gr >= NN) gr = NN - 1;
    const float* xrow = &x[(size_t)gr * FIN];

    for (int k0 = 0; k0 < FIN; k0 += 32) {
        #pragma unroll
        for (int q = 0; q < 4; ++q) {
            float4 v = *(const float4*)(xrow + k0 + skp + q * 4);
            unsigned lo = (unsigned)f2bf(v.x) | ((unsigned)f2bf(v.y) << 16);
            unsigned hi = (unsigned)f2bf(v.z) | ((unsigned)f2bf(v.w) << 16);
            *(uint2*)&xs[srow][skp + q * 4] = make_uint2(lo, hi);
        }
        #pragma unroll
        for (int r = 0; r < 4; ++r) {
            const float* w = W + (size_t)r * FIN * FOUT;
            unsigned pk[4];
            #pragma unroll
            for (int i = 0; i < 8; i += 2) {
                unsigned short b0 = f2bf(w[(size_t)(k0 + skq + i) * FOUT + swn]);
                unsigned short b1 = f2bf(w[(size_t)(k0 + skq + i + 1) * FOUT + swn]);
                pk[i >> 1] = (unsigned)b0 | ((unsigned)b1 << 16);
            }
            *(uint4*)&wt[r][swn][skq] = make_uint4(pk[0], pk[1], pk[2], pk[3]);
        }
        __syncthreads();

        int fr = lane & 15, fk = (lane >> 4) * 8;
        short8 af[4];
        #pragma unroll
        for (int mi = 0; mi < 4; ++mi) af[mi] = *(const short8*)&xs[wm + mi * 16 + fr][fk];
        #pragma unroll
        for (int r = 0; r < 4; ++r) {
            short8 b0 = *(const short8*)&wt[r][wn + fr][fk];
            short8 b1 = *(const short8*)&wt[r][wn + 16 + fr][fk];
            #pragma unroll
            for (int mi = 0; mi < 4; ++mi) {
                acc[r][mi][0] = __builtin_amdgcn_mfma_f32_16x16x32_bf16(af[mi], b0, acc[r][mi][0], 0, 0, 0);
                acc[r][mi][1] = __builtin_amdgcn_mfma_f32_16x16x32_bf16(af[mi], b1, acc[r][mi][1], 0, 0, 0);
            }
        }
        __syncthreads();
    }

    // epilogue: C/D layout col=lane&15, row=(lane>>4)*4+reg
    int fr = lane & 15, frow4 = (lane >> 4) * 4;
    #pragma unroll
    for (int r = 0; r < 4; ++r) {
        unsigned short* hsb = hsb4 + (size_t)r * HSTRIDE;
        const float* ns = nsb4 + (size_t)r * NN;
        #pragma unroll
        for (int mi = 0; mi < 4; ++mi) {
            #pragma unroll
            for (int rg = 0; rg < 4; ++rg) {
                int grow = m0 + wm + mi * 16 + frow4 + rg;
                if (grow < NN) {
                    float sc2 = ns[grow];
                    #pragma unroll
                    for (int ni = 0; ni < 2; ++ni) {
                        int gcol = wn + ni * 16 + fr;
                        hsb[(size_t)grow * FOUT + gcol] = f2bf(acc[r][mi][ni][rg] * sc2);
                    }
                }
            }
        }
    }
    // zero the dummy row NN for each relation (gather padding target)
    if (blockIdx.x == 0 && tid < FOUT) {
        #pragma unroll
        for (int r = 0; r < 4; ++r)
            hsb4[(size_t)r * HSTRIDE + (size_t)NN * FOUT + tid] = 0;
    }
}

// ---------------- fused 4-relation sort+aggregate (32-node buckets, 256 thr) ----------------
// 4 waves x {4 groups x 16 lanes}; group gathers one edge row via uint2/lane.
// Segments padded to x16 (DUMMY -> zero row): branch-free, 4 gathers in flight.
// Small blocks -> up to 8 blocks/CU resident (concurrency test vs R16's 4).
__global__ __launch_bounds__(256, 4) void aggsort4_kernel(const unsigned* __restrict__ pairs4,
                                                          const unsigned* __restrict__ gbaseD4,
                                                          const unsigned* __restrict__ totD4,
                                                          const unsigned short* __restrict__ hsb4,
                                                          float* __restrict__ out) {
    __shared__ unsigned sorted[CAP2];
    __shared__ unsigned cnt[BSZD];       // counts -> cursors
    __shared__ unsigned tdeg[BSZD];      // true degrees
    __shared__ unsigned loff[BSZD + 1];  // padded exclusive offsets
    int tid = threadIdx.x;
    int b = blockIdx.x;
    int wave = tid >> 6, lane = tid & 63;
    int lg = lane >> 4;                  // group 0..3 (edge slot)
    int lp = lane & 15;                  // feature quad position
    const unsigned DUMMY = (unsigned)NN << 7;   // byte offset of zero row

    f32x4 acc4[8];
    #pragma unroll
    for (int i = 0; i < 8; ++i) acc4[i] = (f32x4){0.f, 0.f, 0.f, 0.f};

    for (int r = 0; r < 4; ++r) {
        const unsigned* pairs = pairs4 + (size_t)r * EPR;
        const char* hsbB = (const char*)(hsb4 + (size_t)r * HSTRIDE) + (lp << 3);
        unsigned start = gbaseD4[(size_t)r * NBPD + b];
        int n = (int)totD4[(size_t)r * NBPD + b];

        __syncthreads();                 // protect LDS reuse from prev r
        if (tid < BSZD) cnt[tid] = 0;
        __syncthreads();

        if (n <= CAP2 - 480) {           // pad worst case 15*32
            unsigned rec[CAP2 / 256];
            #pragma unroll
            for (int t = 0; t < CAP2 / 256; ++t) {
                int i = t * 256 + tid;
                rec[t] = 0xFFFFFFFFu;
                if (i < n) {
                    rec[t] = pairs[start + i];
                    atomicAdd(&cnt[rec[t] >> 24], 1u);
                }
            }
            __syncthreads();
            if (wave == 0) {             // padded (to x16) exclusive scan + cursors
                unsigned v = (lane < BSZD) ? cnt[lane] : 0u;
                unsigned pad = (v + 15u) & ~15u;
                unsigned sum = pad;
                #pragma unroll
                for (int o = 1; o < 64; o <<= 1) {
                    unsigned u = __shfl_up(sum, o);
                    if (lane >= o) sum += u;
                }
                if (lane < BSZD) {
                    loff[lane + 1] = sum;
                    tdeg[lane] = v;
                    cnt[lane] = sum - pad;   // cursor = padded exclusive base
                }
                if (lane == 0) loff[0] = 0;
            }
            __syncthreads();
            int ptot = (int)loff[BSZD];
            for (int i = tid; i < ptot; i += 256) sorted[i] = DUMMY;
            __syncthreads();
            #pragma unroll
            for (int t = 0; t < CAP2 / 256; ++t) {
                if (rec[t] != 0xFFFFFFFFu) {
                    unsigned p = atomicAdd(&cnt[rec[t] >> 24], 1u);
                    sorted[p] = rec[t];
                }
            }
            __syncthreads();

            #pragma unroll
            for (int i = 0; i < 8; ++i) {
                int nl = wave * 8 + i;           // 0..31
                int lo = (int)loff[nl], hi = (int)loff[nl + 1];
                f32x4 seg = (f32x4){0.f, 0.f, 0.f, 0.f};
                for (int j0 = lo; j0 < hi; j0 += 16) {
                    unsigned q0 = sorted[j0 + lg];
                    unsigned q1 = sorted[j0 + 4 + lg];
                    unsigned q2 = sorted[j0 + 8 + lg];
                    unsigned q3 = sorted[j0 + 12 + lg];
                    uint2 u0 = *(const uint2*)(hsbB + (q0 & 0xFFFFFFu));
                    uint2 u1 = *(const uint2*)(hsbB + (q1 & 0xFFFFFFu));
                    uint2 u2 = *(const uint2*)(hsbB + (q2 & 0xFFFFFFu));
                    uint2 u3 = *(const uint2*)(hsbB + (q3 & 0xFFFFFFu));
                    unpk(seg, u0); unpk(seg, u1); unpk(seg, u2); unpk(seg, u3);
                }
                unsigned d = tdeg[nl]; if (d < 1u) d = 1u;
                float ndv = rsqrtf((float)d);
                acc4[i].x += seg.x * ndv;
                acc4[i].y += seg.y * ndv;
                acc4[i].z += seg.z * ndv;
                acc4[i].w += seg.w * ndv;
            }
        } else {
            // overflow fallback (not expected): scan-all per node
            for (int i = 0; i < 8; ++i) {
                int nl = wave * 8 + i;
                f32x4 seg = (f32x4){0.f, 0.f, 0.f, 0.f};
                int deg = 0;
                for (int j = 0; j < n; ++j) {
                    unsigned q = pairs[start + j];
                    if ((int)(q >> 24) == nl) {
                        uint2 u = *(const uint2*)(hsbB + (q & 0xFFFFFFu));
                        unpk(seg, u);
                        ++deg;
                    }
                }
                if (deg < 1) deg = 1;
                // all 4 groups hold the full segment; butterfly sums 4 copies
                float nv = rsqrtf((float)deg) * 0.25f;
                acc4[i].x += seg.x * nv; acc4[i].y += seg.y * nv;
                acc4[i].z += seg.z * nv; acc4[i].w += seg.w * nv;
            }
        }
    }

    // cross-group butterfly reduce + tanh + single write (16 lanes x float4)
    #pragma unroll
    for (int i = 0; i < 8; ++i) {
        int nl = wave * 8 + i;
        int node = b * BSZD + nl;        // NN = NBD*BSZD exactly
        f32x4 v = acc4[i];
        v.x += __shfl_xor(v.x, 16); v.y += __shfl_xor(v.y, 16);
        v.z += __shfl_xor(v.z, 16); v.w += __shfl_xor(v.w, 16);
        v.x += __shfl_xor(v.x, 32); v.y += __shfl_xor(v.y, 32);
        v.z += __shfl_xor(v.z, 32); v.w += __shfl_xor(v.w, 32);
        if (lg == 0) {
            float4 o;
            o.x = tanhf(v.x); o.y = tanhf(v.y); o.z = tanhf(v.z); o.w = tanhf(v.w);
            *(float4*)&out[(size_t)node * FOUT + lp * 4] = o;
        }
    }
}

extern "C" void kernel_launch(void* const* d_in, const int* in_sizes, int n_in,
                              void* d_out, int out_size, void* d_ws, size_t ws_size,
                              hipStream_t stream) {
    const float* x = (const float*)d_in[0];
    const float* W = (const float*)d_in[1];
    const int* ei = (const int*)d_in[2];
    float* out = (float*)d_out;

    char* ws = (char*)d_ws;
    size_t o = 0;
    unsigned short* hsb4 = (unsigned short*)(ws + o); o += (size_t)4 * HSTRIDE * 2;    // 51.2 MB
    unsigned* pairs4 = (unsigned*)(ws + o);   o += (size_t)4 * EPR * 4;                // 25.6 MB
    unsigned char* pairs2_4 = (unsigned char*)(ws + o); o += (size_t)4 * EPR;          // 6.4 MB
    unsigned* btabD4 = (unsigned*)(ws + o);   o += (size_t)4 * NBLK * NBPD * 4;        // 19.6 MB
    unsigned* btabS4 = (unsigned*)(ws + o);   o += (size_t)4 * NBLK * NBP * 4;         // 9.8 MB
    unsigned* totD4 = (unsigned*)(ws + o);    o += (size_t)4 * NBPD * 4;
    unsigned* totS4 = (unsigned*)(ws + o);    o += (size_t)4 * NBP * 4;
    unsigned* gbaseD4 = (unsigned*)(ws + o);  o += (size_t)4 * NBPD * 4;
    unsigned* gbaseS4 = (unsigned*)(ws + o);  o += (size_t)4 * NBP * 4;
    float* nsb4 = (float*)(ws + o);           o += (size_t)4 * NN * 4;                 // 1.6 MB

    hist_all_kernel<<<dim3(NBLK, 4), 256, 0, stream>>>(ei, btabD4, btabS4);
    btot_all_kernel<<<dim3(NBPD / 8, 2, 4), 256, 0, stream>>>(btabD4, btabS4, totD4, totS4);
    scan_all_kernel<<<dim3(2, 4), 256, 0, stream>>>(totD4, totS4, gbaseD4, gbaseS4);
    place_all_kernel<<<dim3(NBLK, 4), 256, 0, stream>>>(ei, gbaseD4, btabD4, pairs4,
                                                        gbaseS4, btabS4, pairs2_4);
    srcdeg_all_kernel<<<dim3(NB, 4), 256, 0, stream>>>(pairs2_4, gbaseS4, totS4, nsb4);
    gemm4_kernel<<<(NN + 127) / 128, 256, 0, stream>>>(x, W, hsb4, nsb4);
    aggsort4_kernel<<<NBD, 256, 0, stream>>>(pairs4, gbaseD4, totD4, hsb4, out);
}

// Round 18
// 366.842 us; speedup vs baseline: 1.0738x; 1.0738x over previous
//
#include <hip/hip_runtime.h>
#include <hip/hip_bf16.h>

#define NN 100000
#define EPR 1600000
#define FIN 256
#define FOUT 64
#define BSZ 64            // nodes per bucket
#define NB 1563           // ceil(100000/64)
#define NBP 1568          // padded row stride for tables
#define CHUNK 4096
#define NBLK 391          // ceil(EPR/CHUNK)
#define EPT 16            // edges per thread in hist/place
#define CAP 4096          // LDS sort capacity (incl. pad headroom)
#define HSTRIDE ((size_t)(NN + 1) * FOUT)   // hsb rows per relation incl. zero row

typedef __attribute__((ext_vector_type(8))) short short8;
typedef __attribute__((ext_vector_type(4))) float f32x4;

__device__ __forceinline__ unsigned short f2bf(float f) {
    unsigned u = __float_as_uint(f);
    u = (u + 0x7FFFu + ((u >> 16) & 1u)) >> 16;   // RTN-even
    return (unsigned short)u;
}
__device__ __forceinline__ float uaf(unsigned u) { return __uint_as_float(u); }
__device__ __forceinline__ void unpk(f32x4& seg, uint2 u) {
    seg.x += uaf(u.x << 16); seg.y += uaf(u.x & 0xFFFF0000u);
    seg.z += uaf(u.y << 16); seg.w += uaf(u.y & 0xFFFF0000u);
}

// ---------------- per-(block,relation) bucket histograms ----------------
__global__ __launch_bounds__(256) void hist_all_kernel(const int* __restrict__ ei,
                                                       unsigned* __restrict__ btabD4,
                                                       unsigned* __restrict__ btabS4) {
    __shared__ unsigned hD[NB], hS[NB];
    int tid = threadIdx.x, r = blockIdx.y, blk = blockIdx.x;
    const int* src = ei + (size_t)r * 2 * EPR;
    const int* dst = src + EPR;
    for (int i = tid; i < NB; i += 256) { hD[i] = 0; hS[i] = 0; }
    __syncthreads();
    int e0 = blk * CHUNK;
    #pragma unroll
    for (int t = 0; t < EPT; ++t) {
        int e = e0 + t * 256 + tid;
        if (e < EPR) {
            atomicAdd(&hS[src[e] >> 6], 1u);
            atomicAdd(&hD[dst[e] >> 6], 1u);
        }
    }
    __syncthreads();
    size_t row = ((size_t)r * NBLK + blk) * NBP;
    for (int i = tid; i < NB; i += 256) {
        btabD4[row + i] = hD[i];
        btabS4[row + i] = hS[i];
    }
}

// ---------------- per-bucket exclusive scan over blocks + totals ----------------
__global__ __launch_bounds__(256) void btot_all_kernel(unsigned* __restrict__ btabD4,
                                                       unsigned* __restrict__ btabS4,
                                                       unsigned* __restrict__ totD4,
                                                       unsigned* __restrict__ totS4) {
    int r = blockIdx.z;
    unsigned* tab = (blockIdx.y ? btabS4 : btabD4) + (size_t)r * NBLK * NBP;
    unsigned* tot = (blockIdx.y ? totS4 : totD4) + (size_t)r * NBP;
    __shared__ unsigned tile[NBLK][8];
    int b0 = blockIdx.x * 8;
    for (int idx = threadIdx.x; idx < NBLK * 8; idx += 256) {
        int blk = idx >> 3, bb = idx & 7;
        int b = b0 + bb;
        tile[blk][bb] = (b < NB) ? tab[(size_t)blk * NBP + b] : 0u;
    }
    __syncthreads();
    if (threadIdx.x < 8) {
        int bb = threadIdx.x;
        unsigned s = 0;
        for (int blk = 0; blk < NBLK; ++blk) {
            unsigned v = tile[blk][bb];
            tile[blk][bb] = s;
            s += v;
        }
        if (b0 + bb < NB) tot[b0 + bb] = s;
    }
    __syncthreads();
    for (int idx = threadIdx.x; idx < NBLK * 8; idx += 256) {
        int blk = idx >> 3, bb = idx & 7;
        int b = b0 + bb;
        if (b < NB) tab[(size_t)blk * NBP + b] = tile[blk][bb];
    }
}

// ---------------- exclusive scan of bucket totals -> global bases ----------------
__global__ void scan_all_kernel(const unsigned* __restrict__ totD4, const unsigned* __restrict__ totS4,
                                unsigned* __restrict__ gbaseD4, unsigned* __restrict__ gbaseS4) {
    int r = blockIdx.y;
    const unsigned* tot = (blockIdx.x ? totS4 : totD4) + (size_t)r * NBP;
    unsigned* gb = (blockIdx.x ? gbaseS4 : gbaseD4) + (size_t)r * NBP;
    __shared__ unsigned sc[256];
    int tid = threadIdx.x;
    unsigned loc[8]; unsigned s = 0;
    #pragma unroll
    for (int k = 0; k < 8; ++k) {
        int idx = tid * 8 + k;
        unsigned v = (idx < NB) ? tot[idx] : 0u;
        loc[k] = s; s += v;
    }
    sc[tid] = s; __syncthreads();
    for (int off = 1; off < 256; off <<= 1) {
        unsigned a = (tid >= off) ? sc[tid - off] : 0u;
        __syncthreads(); sc[tid] += a; __syncthreads();
    }
    unsigned texcl = tid ? sc[tid - 1] : 0u;
    #pragma unroll
    for (int k = 0; k < 8; ++k) {
        int idx = tid * 8 + k;
        if (idx < NB) gb[idx] = texcl + loc[k];
    }
}

// ---------------- fused placement: D records then S bytes, edges read ONCE ----------------
// D record layout: bits[23:0] = src byte-offset (src*128), bits[29:24] = dst local id
__global__ __launch_bounds__(256) void place_all_kernel(const int* __restrict__ ei,
                                                        const unsigned* __restrict__ gbaseD4,
                                                        const unsigned* __restrict__ btabD4,
                                                        unsigned* __restrict__ pairs4,
                                                        const unsigned* __restrict__ gbaseS4,
                                                        const unsigned* __restrict__ btabS4,
                                                        unsigned char* __restrict__ pairs2_4) {
    __shared__ unsigned h[NB], hloc[NB], hbase[NB], sc[256];
    __shared__ unsigned buf[CHUNK], buf2[CHUNK];
    int tid = threadIdx.x, blk = blockIdx.x, r = blockIdx.y;
    const int* src = ei + (size_t)r * 2 * EPR;
    const int* dst = src + EPR;
    int e0 = blk * CHUNK;
    int csize = EPR - e0; if (csize > CHUNK) csize = CHUNK;

    // load edges once into registers
    int es[EPT], ed[EPT];
    #pragma unroll
    for (int t = 0; t < EPT; ++t) {
        int e = e0 + t * 256 + tid;
        if (e < EPR) { es[t] = src[e]; ed[t] = dst[e]; }
        else { es[t] = -1; ed[t] = 0; }
    }

    // ================= D phase =================
    for (int i = tid; i < NB; i += 256) h[i] = 0;
    __syncthreads();
    #pragma unroll
    for (int t = 0; t < EPT; ++t)
        if (es[t] >= 0) atomicAdd(&h[ed[t] >> 6], 1u);
    __syncthreads();

    {
        unsigned loc[8]; unsigned s = 0;
        #pragma unroll
        for (int k = 0; k < 8; ++k) {
            int idx = tid * 8 + k;
            unsigned v = (idx < NB) ? h[idx] : 0u;
            loc[k] = s; s += v;
        }
        sc[tid] = s; __syncthreads();
        for (int off = 1; off < 256; off <<= 1) {
            unsigned a = (tid >= off) ? sc[tid - off] : 0u;
            __syncthreads(); sc[tid] += a; __syncthreads();
        }
        unsigned texcl = tid ? sc[tid - 1] : 0u;
        #pragma unroll
        for (int k = 0; k < 8; ++k) {
            int idx = tid * 8 + k;
            if (idx < NB) hloc[idx] = texcl + loc[k];
        }
    }
    __syncthreads();
    {
        const unsigned* gbase = gbaseD4 + (size_t)r * NBP;
        const unsigned* pblk = btabD4 + ((size_t)r * NBLK + blk) * NBP;
        for (int i = tid; i < NB; i += 256) hbase[i] = gbase[i] + pblk[i];
    }
    __syncthreads();
    for (int i = tid; i < NB; i += 256) h[i] = 0;
    __syncthreads();
    #pragma unroll
    for (int t = 0; t < EPT; ++t) {
        if (es[t] >= 0) {
            int b = ed[t] >> 6;
            unsigned rr = atomicAdd(&h[b], 1u);
            unsigned slot = hloc[b] + rr;
            buf[slot] = ((unsigned)es[t] << 7) | ((unsigned)(ed[t] & 63) << 24);
            buf2[slot] = hbase[b] + rr;
        }
    }
    __syncthreads();
    {
        unsigned* pairs = pairs4 + (size_t)r * EPR;
        for (int k = tid; k < csize; k += 256)
            pairs[buf2[k]] = buf[k];
    }
    __syncthreads();

    // ================= S phase (reuses LDS) =================
    for (int i = tid; i < NB; i += 256) h[i] = 0;
    __syncthreads();
    #pragma unroll
    for (int t = 0; t < EPT; ++t)
        if (es[t] >= 0) atomicAdd(&h[es[t] >> 6], 1u);
    __syncthreads();

    {
        unsigned loc[8]; unsigned s = 0;
        #pragma unroll
        for (int k = 0; k < 8; ++k) {
            int idx = tid * 8 + k;
            unsigned v = (idx < NB) ? h[idx] : 0u;
            loc[k] = s; s += v;
        }
        sc[tid] = s; __syncthreads();
        for (int off = 1; off < 256; off <<= 1) {
            unsigned a = (tid >= off) ? sc[tid - off] : 0u;
            __syncthreads(); sc[tid] += a; __syncthreads();
        }
        unsigned texcl = tid ? sc[tid - 1] : 0u;
        #pragma unroll
        for (int k = 0; k < 8; ++k) {
            int idx = tid * 8 + k;
            if (idx < NB) hloc[idx] = texcl + loc[k];
        }
    }
    __syncthreads();
    {
        const unsigned* gbase = gbaseS4 + (size_t)r * NBP;
        const unsigned* pblk = btabS4 + ((size_t)r * NBLK + blk) * NBP;
        for (int i = tid; i < NB; i += 256) hbase[i] = gbase[i] + pblk[i];
    }
    __syncthreads();
    for (int i = tid; i < NB; i += 256) h[i] = 0;
    __syncthreads();
    {
        unsigned char* bufB = (unsigned char*)buf;   // alias D buffer as bytes
        #pragma unroll
        for (int t = 0; t < EPT; ++t) {
            if (es[t] >= 0) {
                int b = es[t] >> 6;
                unsigned rr = atomicAdd(&h[b], 1u);
                unsigned slot = hloc[b] + rr;
                bufB[slot] = (unsigned char)(es[t] & 63);
                buf2[slot] = hbase[b] + rr;
            }
        }
        __syncthreads();
        unsigned char* pairs2 = pairs2_4 + (size_t)r * EPR;
        for (int k = tid; k < csize; k += 256)
            pairs2[buf2[k]] = bufB[k];
    }
}

// ---------------- out-degree per node -> ns = rsqrt ----------------
__global__ void srcdeg_all_kernel(const unsigned char* __restrict__ pairs2_4,
                                  const unsigned* __restrict__ gbaseS4,
                                  const unsigned* __restrict__ totS4,
                                  float* __restrict__ nsb4) {
    __shared__ unsigned cnt[BSZ];
    int tid = threadIdx.x, b = blockIdx.x, r = blockIdx.y;
    const unsigned char* pairs2 = pairs2_4 + (size_t)r * EPR;
    if (tid < BSZ) cnt[tid] = 0;
    __syncthreads();
    unsigned st = gbaseS4[(size_t)r * NBP + b];
    int n = (int)totS4[(size_t)r * NBP + b];
    for (int i = tid; i < n; i += 256)
        atomicAdd(&cnt[pairs2[st + i]], 1u);
    __syncthreads();
    if (tid < BSZ) {
        int node = b * BSZ + tid;
        if (node < NN) {
            unsigned c = cnt[tid]; if (c < 1u) c = 1u;
            nsb4[(size_t)r * NN + node] = rsqrtf((float)c);
        }
    }
}

// ---------------- fused 4-relation bf16 MFMA GEMM: x tile loaded ONCE ----------------
__global__ __launch_bounds__(256, 2) void gemm4_kernel(const float* __restrict__ x,
                                                       const float* __restrict__ W,
                                                       unsigned short* __restrict__ hsb4,
                                                       const float* __restrict__ nsb4) {
    __shared__ unsigned short xs[128][40];      // [m][k] bf16
    __shared__ unsigned short wt[4][64][40];    // [r][n][k] bf16
    int tid = threadIdx.x;
    int wave = tid >> 6, lane = tid & 63;
    int wm = (wave >> 1) * 64;
    int wn = (wave & 1) * 32;
    int m0 = blockIdx.x * 128;

    f32x4 acc[4][4][2];
    #pragma unroll
    for (int r = 0; r < 4; ++r)
        #pragma unroll
        for (int mi = 0; mi < 4; ++mi)
            #pragma unroll
            for (int ni = 0; ni < 2; ++ni)
                acc[r][mi][ni] = (f32x4){0.f, 0.f, 0.f, 0.f};

    int srow = tid >> 1, skp = (tid & 1) * 16;
    int swn = tid >> 2, skq = (tid & 3) * 8;
    int gr = m0 + srow; if (gr >= NN) gr = NN - 1;
    const float* xrow = &x[(size_t)gr * FIN];

    for (int k0 = 0; k0 < FIN; k0 += 32) {
        #pragma unroll
        for (int q = 0; q < 4; ++q) {
            float4 v = *(const float4*)(xrow + k0 + skp + q * 4);
            unsigned lo = (unsigned)f2bf(v.x) | ((unsigned)f2bf(v.y) << 16);
            unsigned hi = (unsigned)f2bf(v.z) | ((unsigned)f2bf(v.w) << 16);
            *(uint2*)&xs[srow][skp + q * 4] = make_uint2(lo, hi);
        }
        #pragma unroll
        for (int r = 0; r < 4; ++r) {
            const float* w = W + (size_t)r * FIN * FOUT;
            unsigned pk[4];
            #pragma unroll
            for (int i = 0; i < 8; i += 2) {
                unsigned short b0 = f2bf(w[(size_t)(k0 + skq + i) * FOUT + swn]);
                unsigned short b1 = f2bf(w[(size_t)(k0 + skq + i + 1) * FOUT + swn]);
                pk[i >> 1] = (unsigned)b0 | ((unsigned)b1 << 16);
            }
            *(uint4*)&wt[r][swn][skq] = make_uint4(pk[0], pk[1], pk[2], pk[3]);
        }
        __syncthreads();

        int fr = lane & 15, fk = (lane >> 4) * 8;
        short8 af[4];
        #pragma unroll
        for (int mi = 0; mi < 4; ++mi) af[mi] = *(const short8*)&xs[wm + mi * 16 + fr][fk];
        #pragma unroll
        for (int r = 0; r < 4; ++r) {
            short8 b0 = *(const short8*)&wt[r][wn + fr][fk];
            short8 b1 = *(const short8*)&wt[r][wn + 16 + fr][fk];
            #pragma unroll
            for (int mi = 0; mi < 4; ++mi) {
                acc[r][mi][0] = __builtin_amdgcn_mfma_f32_16x16x32_bf16(af[mi], b0, acc[r][mi][0], 0, 0, 0);
                acc[r][mi][1] = __builtin_amdgcn_mfma_f32_16x16x32_bf16(af[mi], b1, acc[r][mi][1], 0, 0, 0);
            }
        }
        __syncthreads();
    }

    // epilogue: C/D layout col=lane&15, row=(lane>>4)*4+reg
    int fr = lane & 15, frow4 = (lane >> 4) * 4;
    #pragma unroll
    for (int r = 0; r < 4; ++r) {
        unsigned short* hsb = hsb4 + (size_t)r * HSTRIDE;
        const float* ns = nsb4 + (size_t)r * NN;
        #pragma unroll
        for (int mi = 0; mi < 4; ++mi) {
            #pragma unroll
            for (int rg = 0; rg < 4; ++rg) {
                int grow = m0 + wm + mi * 16 + frow4 + rg;
                if (grow < NN) {
                    float sc2 = ns[grow];
                    #pragma unroll
                    for (int ni = 0; ni < 2; ++ni) {
                        int gcol = wn + ni * 16 + fr;
                        hsb[(size_t)grow * FOUT + gcol] = f2bf(acc[r][mi][ni][rg] * sc2);
                    }
                }
            }
        }
    }
    // zero the dummy row NN for each relation (gather padding target)
    if (blockIdx.x == 0 && tid < FOUT) {
        #pragma unroll
        for (int r = 0; r < 4; ++r)
            hsb4[(size_t)r * HSTRIDE + (size_t)NN * FOUT + tid] = 0;
    }
}

// ---------------- fused 4-relation sort+aggregate (R14 structure) ----------------
// Wave = 4 groups x 16 lanes; group gathers one edge row, lane loads uint2 (4
// bf16 feats). Records are pre-shifted byte offsets. Segments padded to x16
// (DUMMY -> zero row): branch-free inner loop, 4 independent gathers in flight.
__global__ __launch_bounds__(512, 4) void aggsort4_kernel(const unsigned* __restrict__ pairs4,
                                                          const unsigned* __restrict__ gbaseD4,
                                                          const unsigned* __restrict__ totD4,
                                                          const unsigned short* __restrict__ hsb4,
                                                          float* __restrict__ out) {
    __shared__ unsigned sorted[CAP];
    __shared__ unsigned cnt[BSZ];        // counts -> cursors
    __shared__ unsigned tdeg[BSZ];       // true degrees
    __shared__ unsigned loff[BSZ + 1];   // padded exclusive offsets
    int tid = threadIdx.x;
    int b = blockIdx.x;
    int wave = tid >> 6, lane = tid & 63;
    int lg = lane >> 4;                  // group 0..3 (edge slot)
    int lp = lane & 15;                  // feature quad position
    const unsigned DUMMY = (unsigned)NN << 7;   // byte offset of zero row

    f32x4 acc4[8];
    #pragma unroll
    for (int i = 0; i < 8; ++i) acc4[i] = (f32x4){0.f, 0.f, 0.f, 0.f};

    for (int r = 0; r < 4; ++r) {
        const unsigned* pairs = pairs4 + (size_t)r * EPR;
        const char* hsbB = (const char*)(hsb4 + (size_t)r * HSTRIDE) + (lp << 3);
        unsigned start = gbaseD4[(size_t)r * NBP + b];
        int n = (int)totD4[(size_t)r * NBP + b];

        __syncthreads();                 // protect LDS reuse from prev r
        if (tid < BSZ) cnt[tid] = 0;
        __syncthreads();

        if (n <= CAP - 960) {            // pad worst case 15*64
            unsigned rec[CAP / 512];
            #pragma unroll
            for (int t = 0; t < CAP / 512; ++t) {
                int i = t * 512 + tid;
                rec[t] = 0xFFFFFFFFu;
                if (i < n) {
                    rec[t] = pairs[start + i];
                    atomicAdd(&cnt[rec[t] >> 24], 1u);
                }
            }
            __syncthreads();
            if (wave == 0) {             // padded (to x16) exclusive scan + cursors
                unsigned v = cnt[lane];
                unsigned pad = (v + 15u) & ~15u;
                unsigned sum = pad;
                #pragma unroll
                for (int o = 1; o < 64; o <<= 1) {
                    unsigned u = __shfl_up(sum, o);
                    if (lane >= o) sum += u;
                }
                loff[lane + 1] = sum;
                if (lane == 0) loff[0] = 0;
                tdeg[lane] = v;
                cnt[lane] = sum - pad;   // cursor = padded exclusive base
            }
            __syncthreads();
            int ptot = (int)loff[BSZ];
            for (int i = tid; i < ptot; i += 512) sorted[i] = DUMMY;
            __syncthreads();
            #pragma unroll
            for (int t = 0; t < CAP / 512; ++t) {
                if (rec[t] != 0xFFFFFFFFu) {
                    unsigned p = atomicAdd(&cnt[rec[t] >> 24], 1u);
                    sorted[p] = rec[t];
                }
            }
            __syncthreads();

            #pragma unroll
            for (int i = 0; i < 8; ++i) {
                int nl = wave * 8 + i;
                int node = b * BSZ + nl;
                if (node >= NN) break;
                int lo = (int)loff[nl], hi = (int)loff[nl + 1];
                f32x4 seg = (f32x4){0.f, 0.f, 0.f, 0.f};
                for (int j0 = lo; j0 < hi; j0 += 16) {
                    // stage 4 records (independent LDS reads)
                    unsigned q0 = sorted[j0 + lg];
                    unsigned q1 = sorted[j0 + 4 + lg];
                    unsigned q2 = sorted[j0 + 8 + lg];
                    unsigned q3 = sorted[j0 + 12 + lg];
                    // issue 4 independent gathers
                    uint2 u0 = *(const uint2*)(hsbB + (q0 & 0xFFFFFFu));
                    uint2 u1 = *(const uint2*)(hsbB + (q1 & 0xFFFFFFu));
                    uint2 u2 = *(const uint2*)(hsbB + (q2 & 0xFFFFFFu));
                    uint2 u3 = *(const uint2*)(hsbB + (q3 & 0xFFFFFFu));
                    unpk(seg, u0); unpk(seg, u1); unpk(seg, u2); unpk(seg, u3);
                }
                unsigned d = tdeg[nl]; if (d < 1u) d = 1u;
                float ndv = rsqrtf((float)d);
                acc4[i].x += seg.x * ndv;
                acc4[i].y += seg.y * ndv;
                acc4[i].z += seg.z * ndv;
                acc4[i].w += seg.w * ndv;
            }
        } else {
            // overflow fallback (not expected): scan-all per node
            for (int i = 0; i < 8; ++i) {
                int nl = wave * 8 + i;
                int node = b * BSZ + nl;
                if (node >= NN) break;
                f32x4 seg = (f32x4){0.f, 0.f, 0.f, 0.f};
                int deg = 0;
                for (int j = 0; j < n; ++j) {
                    unsigned q = pairs[start + j];
                    if ((int)(q >> 24) == nl) {
                        uint2 u = *(const uint2*)(hsbB + (q & 0xFFFFFFu));
                        unpk(seg, u);
                        ++deg;
                    }
                }
                if (deg < 1) deg = 1;
                // all 4 groups hold the full segment; butterfly sums 4 copies
                float nv = rsqrtf((float)deg) * 0.25f;
                acc4[i].x += seg.x * nv; acc4[i].y += seg.y * nv;
                acc4[i].z += seg.z * nv; acc4[i].w += seg.w * nv;
            }
        }
    }

    // cross-group butterfly reduce + tanh + single write (16 lanes x float4)
    #pragma unroll
    for (int i = 0; i < 8; ++i) {
        int nl = wave * 8 + i;
        int node = b * BSZ + nl;
        f32x4 v = acc4[i];
        v.x += __shfl_xor(v.x, 16); v.y += __shfl_xor(v.y, 16);
        v.z += __shfl_xor(v.z, 16); v.w += __shfl_xor(v.w, 16);
        v.x += __shfl_xor(v.x, 32); v.y += __shfl_xor(v.y, 32);
        v.z += __shfl_xor(v.z, 32); v.w += __shfl_xor(v.w, 32);
        if (node < NN && lg == 0) {
            float4 o;
            o.x = tanhf(v.x); o.y = tanhf(v.y); o.z = tanhf(v.z); o.w = tanhf(v.w);
            *(float4*)&out[(size_t)node * FOUT + lp * 4] = o;
        }
    }
}

extern "C" void kernel_launch(void* const* d_in, const int* in_sizes, int n_in,
                              void* d_out, int out_size, void* d_ws, size_t ws_size,
                              hipStream_t stream) {
    const float* x = (const float*)d_in[0];
    const float* W = (const float*)d_in[1];
    const int* ei = (const int*)d_in[2];
    float* out = (float*)d_out;

    char* ws = (char*)d_ws;
    size_t o = 0;
    unsigned short* hsb4 = (unsigned short*)(ws + o); o += (size_t)4 * HSTRIDE * 2;    // 51.2 MB
    unsigned* pairs4 = (unsigned*)(ws + o);   o += (size_t)4 * EPR * 4;                // 25.6 MB
    unsigned char* pairs2_4 = (unsigned char*)(ws + o); o += (size_t)4 * EPR;          // 6.4 MB
    unsigned* btabD4 = (unsigned*)(ws + o);   o += (size_t)4 * NBLK * NBP * 4;         // 9.8 MB
    unsigned* btabS4 = (unsigned*)(ws + o);   o += (size_t)4 * NBLK * NBP * 4;         // 9.8 MB
    unsigned* totD4 = (unsigned*)(ws + o);    o += (size_t)4 * NBP * 4;
    unsigned* totS4 = (unsigned*)(ws + o);    o += (size_t)4 * NBP * 4;
    unsigned* gbaseD4 = (unsigned*)(ws + o);  o += (size_t)4 * NBP * 4;
    unsigned* gbaseS4 = (unsigned*)(ws + o);  o += (size_t)4 * NBP * 4;
    float* nsb4 = (float*)(ws + o);           o += (size_t)4 * NN * 4;                 // 1.6 MB

    hist_all_kernel<<<dim3(NBLK, 4), 256, 0, stream>>>(ei, btabD4, btabS4);
    btot_all_kernel<<<dim3((NB + 7) / 8, 2, 4), 256, 0, stream>>>(btabD4, btabS4, totD4, totS4);
    scan_all_kernel<<<dim3(2, 4), 256, 0, stream>>>(totD4, totS4, gbaseD4, gbaseS4);
    place_all_kernel<<<dim3(NBLK, 4), 256, 0, stream>>>(ei, gbaseD4, btabD4, pairs4,
                                                        gbaseS4, btabS4, pairs2_4);
    srcdeg_all_kernel<<<dim3(NB, 4), 256, 0, stream>>>(pairs2_4, gbaseS4, totS4, nsb4);
    gemm4_kernel<<<(NN + 127) / 128, 256, 0, stream>>>(x, W, hsb4, nsb4);
    aggsort4_kernel<<<NB, 512, 0, stream>>>(pairs4, gbaseD4, totD4, hsb4, out);
}